// Round 12
// baseline (1756.767 us; speedup 1.0000x reference)
//
#include <hip/hip_runtime.h>
#include <hip/hip_bf16.h>
#include <hip/hip_fp16.h>
#include <float.h>

#define BB 4
#define NN 8192
#define DD 128

typedef __attribute__((ext_vector_type(8))) _Float16 f16x8;
typedef __attribute__((ext_vector_type(16))) float f32x16;
typedef __attribute__((ext_vector_type(4))) unsigned int u32x4;
typedef __attribute__((ext_vector_type(4))) float f32x4;

__device__ __forceinline__ unsigned int pk2h(float a, float b) {
    __half2 h = __floats2half2_rn(a, b);
    return *reinterpret_cast<unsigned int*>(&h);
}

__device__ __forceinline__ f32x4 vmin4(f32x4 a, f32x4 b) {
    f32x4 r;
    r[0] = fminf(a[0], b[0]);
    r[1] = fminf(a[1], b[1]);
    r[2] = fminf(a[2], b[2]);
    r[3] = fminf(a[3], b[3]);
    return r;
}

// ws layout:
//   [0, 512K)       : bfrag u32x4[32768]  (warped-point B-fragments)
//   [512K, 1024K)   : efrag u32x4[32768]  (enc-point B-fragments)
//   [1024K, 1280K)  : rowpart f32[65536]  (per-x mins, both dirs, plain stores)
//   [1280K, 1344K)  : meanEp f32[128][128]

// partial sums of relu(enc @ W1 + b1) -> meanEp; also packs enc B-fragments
__global__ void mean_fe_kernel(const float* __restrict__ enc,
                               const float* __restrict__ W1,
                               const float* __restrict__ b1,
                               float* __restrict__ meanEp,
                               u32x4* __restrict__ efrag) {
    __shared__ float pts[256 * 3];
    __shared__ float red[256];
    int bid = blockIdx.x;            // BB*32 blocks, 256 pts each
    int bt = bid >> 5;
    int chunk = bid & 31;
    int tid = threadIdx.x;
    int k = tid & 127;
    int half = tid >> 7;
    int base = (bt * NN + chunk * 256) * 3;
    for (int i = tid; i < 768; i += 256) pts[i] = enc[base + i];
    float w0 = W1[k], w1 = W1[128 + k], w2 = W1[256 + k], bk = b1[k];
    __syncthreads();
    // pack this thread's enc point as a chamfer B-fragment
    {
        float x0 = pts[tid * 3], x1 = pts[tid * 3 + 1], x2 = pts[tid * 3 + 2];
        float w = x0 * x0 + x1 * x1 + x2 * x2;
        u32x4 v = { pk2h(x0, x1), pk2h(x2, 1.f), pk2h(w, 1.f), 0u };
        efrag[bt * NN + chunk * 256 + tid] = v;
    }
    float acc = 0.f;
    int p0 = half * 128;
#pragma unroll 4
    for (int i = 0; i < 128; ++i) {
        int p = (p0 + i) * 3;
        float v = pts[p] * w0 + pts[p + 1] * w1 + pts[p + 2] * w2 + bk;
        acc += fmaxf(v, 0.f);
    }
    red[tid] = acc;
    __syncthreads();
    if (tid < 128) meanEp[bid * 128 + k] = red[tid] + red[tid + 128];
}

// warped = dec + b2 + f_d @ (W2lo+W2hi) + (meanE/N) @ W2lo
// Also packs warped B-fragments and inits the loss slot.
__global__ void warp_kernel(const float* __restrict__ dec,
                            const float* __restrict__ W1,
                            const float* __restrict__ b1,
                            const float* __restrict__ W2,
                            const float* __restrict__ b2,
                            const float* __restrict__ meanEp,
                            u32x4* __restrict__ bfrag,
                            float* __restrict__ out,
                            float* __restrict__ loss_slot) {
    __shared__ float sW1[384];
    __shared__ float sb1[128];
    __shared__ float sW2[768];
    __shared__ float sME[128];
    int tid = threadIdx.x;
    int idx = blockIdx.x * 256 + tid;   // 32768 threads, one point each
    int bt = idx >> 13;
    for (int i = tid; i < 384; i += 256) sW1[i] = W1[i];
    for (int i = tid; i < 768; i += 256) sW2[i] = W2[i];
    if (tid < 128) {
        sb1[tid] = b1[tid];
        float s = 0.f;
#pragma unroll 8
        for (int c = 0; c < 32; ++c) s += meanEp[(bt * 32 + c) * 128 + tid];
        sME[tid] = s;
    }
    if (idx == 0) *loss_slot = 0.f;
    __syncthreads();
    float d0 = dec[idx * 3], d1 = dec[idx * 3 + 1], d2 = dec[idx * 3 + 2];
    float a0 = 0.f, a1 = 0.f, a2 = 0.f;
    float m0 = 0.f, m1 = 0.f, m2 = 0.f;
#pragma unroll 4
    for (int k = 0; k < 128; ++k) {
        float fd = fmaxf(d0 * sW1[k] + d1 * sW1[128 + k] + d2 * sW1[256 + k] + sb1[k], 0.f);
        float wl0 = sW2[k * 3], wl1 = sW2[k * 3 + 1], wl2 = sW2[k * 3 + 2];
        float wh0 = sW2[(128 + k) * 3], wh1 = sW2[(128 + k) * 3 + 1], wh2 = sW2[(128 + k) * 3 + 2];
        a0 += fd * (wl0 + wh0);
        a1 += fd * (wl1 + wh1);
        a2 += fd * (wl2 + wh2);
        float me = sME[k];
        m0 += me * wl0; m1 += me * wl1; m2 += me * wl2;
    }
    const float invN = 1.0f / NN;
    float o0 = a0 + m0 * invN + b2[0] + d0;
    float o1 = a1 + m1 * invN + b2[1] + d1;
    float o2 = a2 + m2 * invN + b2[2] + d2;
    out[idx * 3]     = o0;
    out[idx * 3 + 1] = o1;
    out[idx * 3 + 2] = o2;
    float w = o0 * o0 + o1 * o1 + o2 * o2;
    u32x4 v = { pk2h(o0, o1), pk2h(o2, 1.f), pk2h(w, 1.f), 0u };
    bfrag[idx] = v;
}

// Two-pass row-only MFMA chamfer. Block = one (dir, bt, xc): 256 x-rows,
// sweeps ALL 8192 y of its batch through double-buffered LDS chunks.
//   A row (x):   [-2x0,-2x1,-2x2, x^2, 1, 1, 0, 0]
//   B col (y):   [ y0,  y1,  y2,  1,  y^2, 1, 0, 0]   -> D = d2 + 1
// Per pair-iter: 2 ds_read_b128 + 4 MFMA + 32 v_min3. No shfl, no atomics.
// Cross-lane row-min happens ONCE per wave per A-frag via padded-LDS transpose.
__global__ __launch_bounds__(256, 2) void chamfer_mfma_kernel(
        const float* __restrict__ enc,
        const float* __restrict__ warped,
        const u32x4* __restrict__ bfrag,
        const u32x4* __restrict__ efrag,
        float* __restrict__ rowpart) {
    __shared__ __align__(16) unsigned int syb[2][4100];   // 2 buffers + zero slots
    __shared__ __align__(16) float scratch[4][32 * 36];   // per-wave transpose pad

    int bid = blockIdx.x;     // dir(2) x bt(4) x xc(32) = 256
    int dir = bid >> 7;
    int bt  = (bid >> 5) & 3;
    int xc  = bid & 31;
    int tid = threadIdx.x;
    int lane = tid & 63, wave = tid >> 6;

    const float* xsrc = dir ? warped : enc;
    const u32x4* ysrc = dir ? efrag : bfrag;

    if (tid < 8) syb[tid >> 2][4096 + (tid & 3)] = 0u;   // zero frags (k=8..15 lanes)

    // two A-fragments per wave (64 x-rows)
    f16x8 af0 = {}, af1 = {};
    int xrow = bt * NN + xc * 256 + wave * 64 + (lane & 31);
    if (lane < 32) {
        int g = xrow * 3;
        float a = xsrc[g], c = xsrc[g + 1], e = xsrc[g + 2];
        float s = a * a + c * c + e * e;
        af0[0] = (_Float16)(-2.f * a); af0[1] = (_Float16)(-2.f * c);
        af0[2] = (_Float16)(-2.f * e); af0[3] = (_Float16)s;
        af0[4] = (_Float16)1.f;        af0[5] = (_Float16)1.f;
        g = (xrow + 32) * 3;
        a = xsrc[g]; c = xsrc[g + 1]; e = xsrc[g + 2];
        s = a * a + c * c + e * e;
        af1[0] = (_Float16)(-2.f * a); af1[1] = (_Float16)(-2.f * c);
        af1[2] = (_Float16)(-2.f * e); af1[3] = (_Float16)s;
        af1[4] = (_Float16)1.f;        af1[5] = (_Float16)1.f;
    }

    float racc0[16], racc1[16];
#pragma unroll
    for (int i = 0; i < 16; ++i) { racc0[i] = FLT_MAX; racc1[i] = FLT_MAX; }
    f32x16 zero = {};

    // prologue: stage chunk 0
    int ybase = bt * NN;
    u32x4 r0 = ysrc[ybase + tid];
    u32x4 r1 = ysrc[ybase + 256 + tid];
    u32x4 r2 = ysrc[ybase + 512 + tid];
    u32x4 r3 = ysrc[ybase + 768 + tid];
    *reinterpret_cast<u32x4*>(&syb[0][tid * 4]) = r0;
    *reinterpret_cast<u32x4*>(&syb[0][(tid + 256) * 4]) = r1;
    *reinterpret_cast<u32x4*>(&syb[0][(tid + 512) * 4]) = r2;
    *reinterpret_cast<u32x4*>(&syb[0][(tid + 768) * 4]) = r3;

    const char* base0 = (const char*)&syb[0][0] + ((lane < 32) ? lane * 16 : 16384);
    const char* base1 = (const char*)&syb[1][0] + ((lane < 32) ? lane * 16 : 16384);
    int str = (lane < 32) ? 512 : 0;

    for (int c = 0; c < 8; ++c) {
        if (c < 7) {   // issue next chunk's global loads (latency hides under compute)
            int yb = ybase + (c + 1) * 1024;
            r0 = ysrc[yb + tid];
            r1 = ysrc[yb + 256 + tid];
            r2 = ysrc[yb + 512 + tid];
            r3 = ysrc[yb + 768 + tid];
        }
        __syncthreads();    // chunk c's LDS writes visible; prev chunk readers done
        const char* base = (c & 1) ? base1 : base0;
#pragma unroll
        for (int t = 0; t < 16; ++t) {
            f16x8 b0 = *(const f16x8*)(base + (2 * t) * str);
            f16x8 b1 = *(const f16x8*)(base + (2 * t + 1) * str);
            f32x16 qa0 = __builtin_amdgcn_mfma_f32_32x32x16_f16(af0, b0, zero, 0, 0, 0);
            f32x16 qa1 = __builtin_amdgcn_mfma_f32_32x32x16_f16(af0, b1, zero, 0, 0, 0);
            f32x16 qb0 = __builtin_amdgcn_mfma_f32_32x32x16_f16(af1, b0, zero, 0, 0, 0);
            f32x16 qb1 = __builtin_amdgcn_mfma_f32_32x32x16_f16(af1, b1, zero, 0, 0, 0);
#pragma unroll
            for (int i = 0; i < 16; ++i) {
                racc0[i] = fminf(racc0[i], fminf(qa0[i], qa1[i]));   // v_min3
                racc1[i] = fminf(racc1[i], fminf(qb0[i], qb1[i]));
            }
        }
        if (c < 7) {   // write next chunk into the other buffer
            int d = (c + 1) & 1;
            *reinterpret_cast<u32x4*>(&syb[d][tid * 4]) = r0;
            *reinterpret_cast<u32x4*>(&syb[d][(tid + 256) * 4]) = r1;
            *reinterpret_cast<u32x4*>(&syb[d][(tid + 512) * 4]) = r2;
            *reinterpret_cast<u32x4*>(&syb[d][(tid + 768) * 4]) = r3;
        }
    }

    // epilogue: per-frag cross-lane row-min via per-wave padded transpose
    float* sc = &scratch[wave][0];
    int hi = lane >> 5, col = lane & 31;
    int outbase = dir * (BB * NN) + bt * NN + xc * 256 + wave * 64;
#pragma unroll
    for (int a = 0; a < 2; ++a) {
        const float* rc = a ? racc1 : racc0;
#pragma unroll
        for (int i = 0; i < 16; ++i) {
            int row = (i & 3) + 8 * (i >> 2) + 4 * hi;
            sc[row * 36 + col] = rc[i];
        }
        __builtin_amdgcn_wave_barrier();   // keep in-wave ds order (compiler adds lgkmcnt)
        if (lane < 32) {
            f32x4 v0 = *(const f32x4*)&sc[lane * 36 + 0];
            f32x4 v1 = *(const f32x4*)&sc[lane * 36 + 4];
            f32x4 v2 = *(const f32x4*)&sc[lane * 36 + 8];
            f32x4 v3 = *(const f32x4*)&sc[lane * 36 + 12];
            f32x4 v4 = *(const f32x4*)&sc[lane * 36 + 16];
            f32x4 v5 = *(const f32x4*)&sc[lane * 36 + 20];
            f32x4 v6 = *(const f32x4*)&sc[lane * 36 + 24];
            f32x4 v7 = *(const f32x4*)&sc[lane * 36 + 28];
            f32x4 m01 = vmin4(vmin4(v0, v1), vmin4(v2, v3));
            f32x4 m23 = vmin4(vmin4(v4, v5), vmin4(v6, v7));
            f32x4 mm = vmin4(m01, m23);
            float m = fminf(fminf(mm[0], mm[1]), fminf(mm[2], mm[3]));
            rowpart[outbase + a * 32 + lane] = m;
        }
        __builtin_amdgcn_wave_barrier();   // a=1 writes must not pass a=0 reads
    }
}

// sum all 65536 row-mins -> loss (values carry +1 bias each; /32768 then -2)
__global__ void reduce_loss_kernel(const float* __restrict__ rowpart,
                                   float* __restrict__ loss_slot) {
    __shared__ float red[256];
    int tid = threadIdx.x;
    int idx = blockIdx.x * 256 + tid;   // 64 blocks
    float s = 0.f;
#pragma unroll
    for (int i = 0; i < 4; ++i)
        s += rowpart[idx + i * 16384];
    red[tid] = s;
    __syncthreads();
    for (int off = 128; off > 0; off >>= 1) {
        if (tid < off) red[tid] += red[tid + off];
        __syncthreads();
    }
    if (tid == 0) {
        float v = red[0] * (1.0f / (BB * NN));
        if (blockIdx.x == 0) v -= 2.0f;
        atomicAdd(loss_slot, v);
    }
}

extern "C" void kernel_launch(void* const* d_in, const int* in_sizes, int n_in,
                              void* d_out, int out_size, void* d_ws, size_t ws_size,
                              hipStream_t stream) {
    const float* enc = (const float*)d_in[0];
    const float* dec = (const float*)d_in[1];
    const float* W1  = (const float*)d_in[2];
    const float* b1  = (const float*)d_in[3];
    const float* W2  = (const float*)d_in[4];
    const float* b2  = (const float*)d_in[5];
    float* out = (float*)d_out;

    u32x4* bfrag = (u32x4*)d_ws;                                     // 512 KB
    u32x4* efrag = (u32x4*)((char*)d_ws + (512u << 10));             // 512 KB
    float* rowpart = (float*)((char*)d_ws + (1024u << 10));          // 256 KB
    float* meanEp  = (float*)((char*)d_ws + (1280u << 10));          // 64 KB
    float* loss_slot = out + BB * NN * 3;

    mean_fe_kernel<<<BB * 32, 256, 0, stream>>>(enc, W1, b1, meanEp, efrag);
    warp_kernel<<<BB * NN / 256, 256, 0, stream>>>(dec, W1, b1, W2, b2, meanEp,
                                                   bfrag, out, loss_slot);
    chamfer_mfma_kernel<<<256, 256, 0, stream>>>(enc, out, bfrag, efrag, rowpart);
    reduce_loss_kernel<<<64, 256, 0, stream>>>(rowpart, loss_slot);
}

// Round 13
// 46.135 us; speedup vs baseline: 38.0786x; 38.0786x over previous
//
#include <hip/hip_runtime.h>
#include <hip/hip_bf16.h>
#include <hip/hip_fp16.h>
#include <float.h>

#define BB 4
#define NN 8192
#define DD 128

typedef __attribute__((ext_vector_type(8))) _Float16 f16x8;
typedef __attribute__((ext_vector_type(16))) float f32x16;
typedef __attribute__((ext_vector_type(4))) unsigned int u32x4;

__device__ __forceinline__ unsigned int pk2h(float a, float b) {
    __half2 h = __floats2half2_rn(a, b);
    return *reinterpret_cast<unsigned int*>(&h);
}

// ws layout:
//   [0, 262144)        : buf = rowbuf uint[32768] ++ colbuf uint[32768]
//                        (raw f32 bits of biased (+1) mins; all > 0 so
//                         uint order == float order)
//   [262144, 278528)   : meanEp f32[4][32][128] partial sums

// partial sums of relu(enc @ W1 + b1) -> meanEp (plain writes, no atomics)
__global__ void mean_fe_kernel(const float* __restrict__ enc,
                               const float* __restrict__ W1,
                               const float* __restrict__ b1,
                               float* __restrict__ meanEp) {
    __shared__ float pts[256 * 3];
    __shared__ float red[256];
    int bid = blockIdx.x;            // BB*32 blocks, 256 pts each
    int bt = bid >> 5;
    int chunk = bid & 31;
    int tid = threadIdx.x;
    int k = tid & 127;
    int half = tid >> 7;
    int base = (bt * NN + chunk * 256) * 3;
    for (int i = tid; i < 768; i += 256) pts[i] = enc[base + i];
    float w0 = W1[k], w1 = W1[128 + k], w2 = W1[256 + k], bk = b1[k];
    __syncthreads();
    float acc = 0.f;
    int p0 = half * 128;
#pragma unroll 4
    for (int i = 0; i < 128; ++i) {
        int p = (p0 + i) * 3;
        float v = pts[p] * w0 + pts[p + 1] * w1 + pts[p + 2] * w2 + bk;
        acc += fmaxf(v, 0.f);
    }
    red[tid] = acc;
    __syncthreads();
    if (tid < 128) meanEp[bid * 128 + k] = red[tid] + red[tid + 128];
}

// warped = dec + b2 + f_d @ (W2lo+W2hi) + (meanE/N) @ W2lo
// Also: reduce meanEp, init min-buf to +inf bits, init loss slot.
__global__ void warp_kernel(const float* __restrict__ dec,
                            const float* __restrict__ W1,
                            const float* __restrict__ b1,
                            const float* __restrict__ W2,
                            const float* __restrict__ b2,
                            const float* __restrict__ meanEp,
                            unsigned int* __restrict__ buf,
                            float* __restrict__ out,
                            float* __restrict__ loss_slot) {
    __shared__ float sW1[384];
    __shared__ float sb1[128];
    __shared__ float sW2[768];
    __shared__ float sME[128];
    int tid = threadIdx.x;
    int idx = blockIdx.x * 256 + tid;   // 32768 threads, one point each
    int bt = idx >> 13;
    for (int i = tid; i < 384; i += 256) sW1[i] = W1[i];
    for (int i = tid; i < 768; i += 256) sW2[i] = W2[i];
    if (tid < 128) {
        sb1[tid] = b1[tid];
        float s = 0.f;
#pragma unroll 8
        for (int c = 0; c < 32; ++c) s += meanEp[(bt * 32 + c) * 128 + tid];
        sME[tid] = s;
    }
    // init the min buffers (stream-ordered before chamfer)
    buf[idx] = 0x7F7FFFFFu;
    buf[32768 + idx] = 0x7F7FFFFFu;
    if (idx == 0) *loss_slot = 0.f;
    __syncthreads();
    float d0 = dec[idx * 3], d1 = dec[idx * 3 + 1], d2 = dec[idx * 3 + 2];
    float a0 = 0.f, a1 = 0.f, a2 = 0.f;
    float m0 = 0.f, m1 = 0.f, m2 = 0.f;
#pragma unroll 4
    for (int k = 0; k < 128; ++k) {
        float fd = fmaxf(d0 * sW1[k] + d1 * sW1[128 + k] + d2 * sW1[256 + k] + sb1[k], 0.f);
        float wl0 = sW2[k * 3], wl1 = sW2[k * 3 + 1], wl2 = sW2[k * 3 + 2];
        float wh0 = sW2[(128 + k) * 3], wh1 = sW2[(128 + k) * 3 + 1], wh2 = sW2[(128 + k) * 3 + 2];
        a0 += fd * (wl0 + wh0);
        a1 += fd * (wl1 + wh1);
        a2 += fd * (wl2 + wh2);
        float me = sME[k];
        m0 += me * wl0; m1 += me * wl1; m2 += me * wl2;
    }
    const float invN = 1.0f / NN;
    out[idx * 3]     = a0 + m0 * invN + b2[0] + d0;
    out[idx * 3 + 1] = a1 + m1 * invN + b2[1] + d1;
    out[idx * 3 + 2] = a2 + m2 * invN + b2[2] + d2;
}

// Dual-axis MFMA chamfer. One d2 tile serves BOTH directions:
//   A row r (enc):  [-2x0,-2x1,-2x2, x^2, 1, 1, 0, 0]
//   B col c (warp): [ y0,  y1,  y2,  1,  y^2, 1, 0, 0]
//   D[r][c] = d2 + 1   (bias keeps everything positive -> raw-bit uint min)
// Row-min (enc side) via racc accumulation + LDS transpose.
// Col-min (warp side) via in-lane 16-reg tree + LDS atomicMin.
__global__ __launch_bounds__(512, 4) void chamfer_mfma_kernel(
        const float* __restrict__ enc,
        const float* __restrict__ warped,
        unsigned int* __restrict__ buf) {
    __shared__ __align__(16) union {
        unsigned int syb[1024 * 4 + 4];   // B frags (16B/y) + zero slot
        float rmin[256 * 33];             // padded row-min transpose
    } sh;
    __shared__ unsigned int colmin[1024];

    int bid = blockIdx.x;     // b(4) x xc(32) x ys(8) = 1024
    int bt = bid >> 8;
    int xc = (bid >> 3) & 31;
    int ys = bid & 7;
    int tid = threadIdx.x;
    int lane = tid & 63, wave = tid >> 6;

    // stage B fragments for 1024 warped points
    int ybase = bt * NN + ys * 1024;
#pragma unroll
    for (int i = 0; i < 2; ++i) {
        int p = tid + i * 512;
        int g = (ybase + p) * 3;
        float y0 = warped[g], y1 = warped[g + 1], y2 = warped[g + 2];
        float w = y0 * y0 + y1 * y1 + y2 * y2;
        u32x4 v = { pk2h(y0, y1), pk2h(y2, 1.f), pk2h(w, 1.f), 0u };
        *reinterpret_cast<u32x4*>(&sh.syb[p * 4]) = v;
    }
    if (tid < 4) sh.syb[4096 + tid] = 0u;        // zero frag for k=8..15 lanes
    if (tid < 512) { colmin[tid] = 0x7F7FFFFFu; colmin[tid + 512] = 0x7F7FFFFFu; }

    // A fragment: 32 enc points per wave
    f16x8 afrag = {};
    int xbase = bt * NN + xc * 256 + wave * 32;
    if (lane < 32) {
        int g = (xbase + lane) * 3;
        float a = enc[g], c = enc[g + 1], e = enc[g + 2];
        float s = a * a + c * c + e * e;
        afrag[0] = (_Float16)(-2.f * a);
        afrag[1] = (_Float16)(-2.f * c);
        afrag[2] = (_Float16)(-2.f * e);
        afrag[3] = (_Float16)s;
        afrag[4] = (_Float16)1.f;
        afrag[5] = (_Float16)1.f;
    }
    __syncthreads();

    const char* base = (const char*)sh.syb + ((lane < 32) ? lane * 16 : 16384);
    int str = (lane < 32) ? 512 : 0;
    int col = lane & 31;

    float racc[16];
#pragma unroll
    for (int i = 0; i < 16; ++i) racc[i] = FLT_MAX;
    f32x16 zero = {};

    f16x8 b0 = *(const f16x8*)(base);
    f16x8 b1 = *(const f16x8*)(base + str);
#pragma unroll
    for (int t = 0; t < 16; ++t) {
        f16x8 n0 = b0, n1 = b1;
        if (t < 15) {
            n0 = *(const f16x8*)(base + (2 * t + 2) * str);
            n1 = *(const f16x8*)(base + (2 * t + 3) * str);
        }
        f32x16 q0 = __builtin_amdgcn_mfma_f32_32x32x16_f16(afrag, b0, zero, 0, 0, 0);
        f32x16 q1 = __builtin_amdgcn_mfma_f32_32x32x16_f16(afrag, b1, zero, 0, 0, 0);
        // row-side: accumulate elementwise min (v_min3)
#pragma unroll
        for (int i = 0; i < 16; ++i)
            racc[i] = fminf(racc[i], fminf(q0[i], q1[i]));
        // col-side: in-lane tree over 16 rows, then LDS atomicMin
        float c00 = fminf(q0[0], fminf(q0[1], q0[2]));
        float c01 = fminf(q0[3], fminf(q0[4], q0[5]));
        float c02 = fminf(q0[6], fminf(q0[7], q0[8]));
        float c03 = fminf(q0[9], fminf(q0[10], q0[11]));
        float c04 = fminf(q0[12], fminf(q0[13], q0[14]));
        float cm0 = fminf(fminf(q0[15], fminf(c00, c01)), fminf(c02, fminf(c03, c04)));
        float c10 = fminf(q1[0], fminf(q1[1], q1[2]));
        float c11 = fminf(q1[3], fminf(q1[4], q1[5]));
        float c12 = fminf(q1[6], fminf(q1[7], q1[8]));
        float c13 = fminf(q1[9], fminf(q1[10], q1[11]));
        float c14 = fminf(q1[12], fminf(q1[13], q1[14]));
        float cm1 = fminf(fminf(q1[15], fminf(c10, c11)), fminf(c12, fminf(c13, c14)));
        atomicMin(&colmin[2 * t * 32 + col], __float_as_uint(cm0));
        atomicMin(&colmin[(2 * t + 1) * 32 + col], __float_as_uint(cm1));
        b0 = n0; b1 = n1;
    }

    // row-min across 32 cols: transpose via padded LDS (overwrites syb)
    __syncthreads();
    int half = lane >> 5;
#pragma unroll
    for (int i = 0; i < 16; ++i) {
        int row = wave * 32 + (i & 3) + 8 * (i >> 2) + 4 * half;
        sh.rmin[row * 33 + col] = racc[i];
    }
    __syncthreads();
    if (tid < 256) {
        float m = sh.rmin[tid * 33];
#pragma unroll
        for (int j = 1; j < 32; ++j) m = fminf(m, sh.rmin[tid * 33 + j]);
        atomicMin(&buf[bt * NN + xc * 256 + tid], __float_as_uint(m));
    }
    // col-side global combine (32 xc partials per col)
    atomicMin(&buf[32768 + bt * NN + ys * 1024 + tid], colmin[tid]);
    atomicMin(&buf[32768 + bt * NN + ys * 1024 + tid + 512], colmin[tid + 512]);
}

__global__ void reduce_loss_kernel(const unsigned int* __restrict__ buf,
                                   float* __restrict__ loss_slot) {
    __shared__ float red[256];
    int tid = threadIdx.x;
    int idx = blockIdx.x * 256 + tid;   // 64 blocks over 65536 entries
    float s = 0.f;
#pragma unroll
    for (int i = 0; i < 4; ++i)
        s += __uint_as_float(buf[idx + i * 16384]);
    red[tid] = s;
    __syncthreads();
    for (int off = 128; off > 0; off >>= 1) {
        if (tid < off) red[tid] += red[tid + off];
        __syncthreads();
    }
    if (tid == 0) {
        float v = red[0] * (1.0f / (BB * NN));
        if (blockIdx.x == 0) v -= 2.0f;          // remove the +1 bias (both dirs)
        atomicAdd(loss_slot, v);
    }
}

extern "C" void kernel_launch(void* const* d_in, const int* in_sizes, int n_in,
                              void* d_out, int out_size, void* d_ws, size_t ws_size,
                              hipStream_t stream) {
    const float* enc = (const float*)d_in[0];
    const float* dec = (const float*)d_in[1];
    const float* W1  = (const float*)d_in[2];
    const float* b1  = (const float*)d_in[3];
    const float* W2  = (const float*)d_in[4];
    const float* b2  = (const float*)d_in[5];
    float* out = (float*)d_out;

    unsigned int* buf = (unsigned int*)d_ws;                    // 256 KB
    float* meanEp = (float*)((char*)d_ws + 262144);             // 16 KB
    float* loss_slot = out + BB * NN * 3;

    mean_fe_kernel<<<BB * 32, 256, 0, stream>>>(enc, W1, b1, meanEp);
    warp_kernel<<<BB * NN / 256, 256, 0, stream>>>(dec, W1, b1, W2, b2, meanEp,
                                                   buf, out, loss_slot);
    chamfer_mfma_kernel<<<BB * 32 * 8, 512, 0, stream>>>(enc, out, buf);
    reduce_loss_kernel<<<64, 256, 0, stream>>>(buf, loss_slot);
}